// Round 5
// baseline (1018.434 us; speedup 1.0000x reference)
//
#include <hip/hip_runtime.h>

#define N_NODES 100000
#define N_EDGES 3200000
#define DIM 128
#define LN_EPS 1e-5f
#define NBLK 391              // ceil(N_NODES / 256)
#define N_BUCKETS 1563        // ceil(N_NODES / 64)
#define BUCKET_CAP 4096       // mean 2048, sigma ~45 -> no overflow

// ---- workspace layout (4-byte elements) ----
#define WS_CNT    0           // int  [N_NODES]
#define WS_OFF    100000      // int  [N_NODES+1]
#define WS_DIS    200004      // float[N_NODES]
#define WS_BIN    300004      // int  [N_EDGES]   packed (row | (col&63)<<17)
#define WS_BSUM   3500004     // int  [512]
#define WS_BEXC   3500516     // int  [512]
#define WS_BCUR   3501028     // int  [N_BUCKETS]
#define WS_WB     3502592     // 16384 bf16 (8192 ints)

typedef __attribute__((ext_vector_type(8))) short short8;   // bf16x8 MFMA frag
typedef __attribute__((ext_vector_type(4))) float floatx4;  // MFMA acc

__device__ __forceinline__ short f2bf(float f) {
    unsigned u = __float_as_uint(f);
    unsigned r = (u + 0x7FFFu + ((u >> 16) & 1u)) >> 16;   // RNE
    return (short)r;
}

// ---- degree count ----
__global__ void k_count(const int* __restrict__ col, int* __restrict__ cnt) {
    int e = blockIdx.x * blockDim.x + threadIdx.x;
    if (e < N_EDGES) atomicAdd(&cnt[col[e]], 1);
}

__global__ void k_blockreduce(const int* __restrict__ cnt, int* __restrict__ bsum) {
    __shared__ int s[256];
    int i = blockIdx.x * 256 + threadIdx.x;
    s[threadIdx.x] = (i < N_NODES) ? cnt[i] : 0;
    __syncthreads();
    for (int st = 128; st > 0; st >>= 1) {
        if (threadIdx.x < st) s[threadIdx.x] += s[threadIdx.x + st];
        __syncthreads();
    }
    if (threadIdx.x == 0) bsum[blockIdx.x] = s[0];
}

__global__ void k_scanbsums(const int* __restrict__ bsum, int* __restrict__ bexc,
                            int* __restrict__ off) {
    __shared__ int s[512];
    int t = threadIdx.x;
    int v0 = (t < NBLK) ? bsum[t] : 0;
    s[t] = v0;
    __syncthreads();
    for (int st = 1; st < 512; st <<= 1) {
        int v = (t >= st) ? s[t - st] : 0;
        __syncthreads();
        s[t] += v;
        __syncthreads();
    }
    if (t < NBLK) bexc[t] = s[t] - v0;
    if (t == 0) off[N_NODES] = N_EDGES;
}

__global__ void k_blockscan(const int* __restrict__ cnt, const int* __restrict__ bexc,
                            int* __restrict__ off) {
    __shared__ int s[256];
    int i = blockIdx.x * 256 + threadIdx.x;
    int v = (i < N_NODES) ? cnt[i] : 0;
    s[threadIdx.x] = v;
    __syncthreads();
    for (int st = 1; st < 256; st <<= 1) {
        int u = (threadIdx.x >= st) ? s[threadIdx.x - st] : 0;
        __syncthreads();
        s[threadIdx.x] += u;
        __syncthreads();
    }
    if (i < N_NODES) off[i] = bexc[blockIdx.x] + s[threadIdx.x] - v;  // exclusive
}

__global__ void k_dis(const int* __restrict__ cnt, float* __restrict__ dis) {
    int i = blockIdx.x * blockDim.x + threadIdx.x;
    if (i < N_NODES) dis[i] = rsqrtf(1.0f + (float)cnt[i]);
}

// ---- bucket cursors: bcur[b] = off[b*64] ----
__global__ void k_bcur(const int* __restrict__ off, int* __restrict__ bcur) {
    int b = blockIdx.x * blockDim.x + threadIdx.x;
    if (b < N_BUCKETS) bcur[b] = off[b << 6];
}

// ---- coarse scatter: append packed (row | (col&63)<<17) into the target's bucket ----
__global__ void k_binpack(const int* __restrict__ row, const int* __restrict__ col,
                          int* __restrict__ bcur, int* __restrict__ binned) {
    int e = blockIdx.x * blockDim.x + threadIdx.x;
    if (e < N_EDGES) {
        int c = col[e];
        int pos = atomicAdd(&bcur[c >> 6], 1);
        binned[pos] = row[e] | ((c & 63) << 17);
    }
}

// ---- fused fine-sort (LDS) + gather: one block per bucket of 64 targets ----
__global__ void __launch_bounds__(256) k_bucket_gather(
        const float* __restrict__ x,
        const float* __restrict__ dis,
        const int* __restrict__ binned,
        const int* __restrict__ off,
        float* __restrict__ agg) {
    __shared__ int lcsr[BUCKET_CAP];
    __shared__ int lcur[64];
    int b = blockIdx.x;
    int node0 = b << 6;
    int nt = min(64, N_NODES - node0);    // 64, or 32 for the last bucket
    int tid = threadIdx.x;
    int base = off[node0];
    int cnt_b = off[node0 + nt] - base;
    if (tid < nt) lcur[tid] = off[node0 + tid] - base;
    __syncthreads();

    // fine scatter into LDS-local CSR (LDS atomics; no global scattered writes)
    for (int k = tid; k < cnt_b; k += 256) {
        int p = binned[base + k];
        int cl = p >> 17;
        int pos = atomicAdd(&lcur[cl], 1);
        lcsr[pos] = p & 0x1FFFF;
    }
    __syncthreads();

    // gather (R2-verified inner loop, sources from LDS)
    int wave = tid >> 6, lane = tid & 63;
    const float2* x2 = (const float2*)x;
    for (int u = 0; u < 16; ++u) {
        int node = node0 + wave * 16 + u;
        if (node >= N_NODES) break;
        int start = off[node] - base, end = off[node + 1] - base;
        float2 acc = make_float2(0.f, 0.f);
        for (int bs = start; bs < end; bs += 64) {
            int n = min(64, end - bs);
            int s = 0;
            float w = 0.f;
            if (lane < n) { s = lcsr[bs + lane]; w = dis[s]; }
            for (int j = 0; j < n; ++j) {
                int sj = __shfl(s, j, 64);
                float wj = __shfl(w, j, 64);
                float2 xv = x2[(size_t)sj * 64 + lane];   // 512B coalesced row read
                acc.x += wj * xv.x;
                acc.y += wj * xv.y;
            }
        }
        float di = dis[node];
        float2 xi = x2[(size_t)node * 64 + lane];
        acc.x = (acc.x + di * xi.x) * di;
        acc.y = (acc.y + di * xi.y) * di;
        ((float2*)agg)[(size_t)node * 64 + lane] = acc;
    }
}

// ---- W fp32 -> bf16 ----
__global__ void k_wconv(const float* __restrict__ W, short* __restrict__ Wb) {
    int i = blockIdx.x * 256 + threadIdx.x;
    if (i < DIM * DIM) Wb[i] = f2bf(W[i]);
}

// ---- linear + LayerNorm via bf16 MFMA: one wave per 16 nodes, in-place on agg/out ----
// mfma_f32_16x16x32_bf16: A[m=lane&15][k=(lane>>4)*8+j]; C/D: col=lane&15, row=(lane>>4)*4+reg
// NOTE: agg/out intentionally NOT __restrict__ (same buffer, in-place).
__global__ void __launch_bounds__(256) k_linear_ln_mfma(
        const float* agg,
        const short* __restrict__ Wb,
        const float* __restrict__ bias,
        const float* __restrict__ gamma,
        const float* __restrict__ beta,
        float* out) {
    int wave = threadIdx.x >> 6;
    int lane = threadIdx.x & 63;
    int i0 = (blockIdx.x * 4 + wave) * 16;   // 16 nodes per wave; 100000 % 16 == 0
    if (i0 >= N_NODES) return;
    int m = lane & 15;
    int q = lane >> 4;

    floatx4 acc[8];
#pragma unroll
    for (int t = 0; t < 8; ++t) acc[t] = (floatx4){0.f, 0.f, 0.f, 0.f};

#pragma unroll
    for (int s = 0; s < 4; ++s) {
        int k0 = s * 32 + q * 8;
        const float* ap = agg + (size_t)(i0 + m) * DIM + k0;
        float4 a0 = *(const float4*)ap;
        float4 a1 = *(const float4*)(ap + 4);
        short8 af;
        af[0] = f2bf(a0.x); af[1] = f2bf(a0.y); af[2] = f2bf(a0.z); af[3] = f2bf(a0.w);
        af[4] = f2bf(a1.x); af[5] = f2bf(a1.y); af[6] = f2bf(a1.z); af[7] = f2bf(a1.w);
#pragma unroll
        for (int t = 0; t < 8; ++t) {
            short8 bf = *(const short8*)(Wb + (size_t)(t * 16 + m) * DIM + k0);
            acc[t] = __builtin_amdgcn_mfma_f32_16x16x32_bf16(af, bf, acc[t], 0, 0, 0);
        }
    }

    float bv[8], gv[8], btv[8];
#pragma unroll
    for (int t = 0; t < 8; ++t) {
        int dim = t * 16 + m;
        bv[t] = bias[dim]; gv[t] = gamma[dim]; btv[t] = beta[dim];
    }
    float S[4], S2[4];
#pragma unroll
    for (int r = 0; r < 4; ++r) {
        float s = 0.f, s2 = 0.f;
#pragma unroll
        for (int t = 0; t < 8; ++t) {
            float v = acc[t][r] + bv[t];
            s += v; s2 += v * v;
        }
        S[r] = s; S2[r] = s2;
    }
#pragma unroll
    for (int mask = 1; mask < 16; mask <<= 1) {
#pragma unroll
        for (int r = 0; r < 4; ++r) {
            S[r]  += __shfl_xor(S[r],  mask, 64);
            S2[r] += __shfl_xor(S2[r], mask, 64);
        }
    }
#pragma unroll
    for (int r = 0; r < 4; ++r) {
        float mean = S[r] * (1.0f / DIM);
        float var  = S2[r] * (1.0f / DIM) - mean * mean;
        float inv  = rsqrtf(var + LN_EPS);
        int node = i0 + q * 4 + r;
#pragma unroll
        for (int t = 0; t < 8; ++t) {
            float v = acc[t][r] + bv[t];
            out[(size_t)node * DIM + t * 16 + m] = (v - mean) * inv * gv[t] + btv[t];
        }
    }
}

extern "C" void kernel_launch(void* const* d_in, const int* in_sizes, int n_in,
                              void* d_out, int out_size, void* d_ws, size_t ws_size,
                              hipStream_t stream) {
    const float* x     = (const float*)d_in[0];
    const int*   row   = (const int*)d_in[1];                // edge_index[0] (sources)
    const int*   col   = ((const int*)d_in[1]) + N_EDGES;    // edge_index[1] (targets)
    const float* W     = (const float*)d_in[2];
    const float* bias  = (const float*)d_in[3];
    const float* gamma = (const float*)d_in[4];
    const float* beta  = (const float*)d_in[5];
    float* out = (float*)d_out;

    int*   wsi    = (int*)d_ws;
    int*   cnt    = wsi + WS_CNT;
    int*   off    = wsi + WS_OFF;
    float* dis    = (float*)(wsi + WS_DIS);
    int*   binned = wsi + WS_BIN;
    int*   bsum   = wsi + WS_BSUM;
    int*   bexc   = wsi + WS_BEXC;
    int*   bcur   = wsi + WS_BCUR;
    short* Wb     = (short*)(wsi + WS_WB);

    hipMemsetAsync(cnt, 0, N_NODES * sizeof(int), stream);

    k_wconv<<<(DIM * DIM + 255) / 256, 256, 0, stream>>>(W, Wb);
    k_count<<<(N_EDGES + 255) / 256, 256, 0, stream>>>(col, cnt);
    k_blockreduce<<<NBLK, 256, 0, stream>>>(cnt, bsum);
    k_scanbsums<<<1, 512, 0, stream>>>(bsum, bexc, off);
    k_blockscan<<<NBLK, 256, 0, stream>>>(cnt, bexc, off);
    k_dis<<<NBLK, 256, 0, stream>>>(cnt, dis);
    k_bcur<<<(N_BUCKETS + 255) / 256, 256, 0, stream>>>(off, bcur);
    k_binpack<<<(N_EDGES + 255) / 256, 256, 0, stream>>>(row, col, bcur, binned);

    k_bucket_gather<<<N_BUCKETS, 256, 0, stream>>>(x, dis, binned, off, out);

    k_linear_ln_mfma<<<(N_NODES / 16 + 3) / 4, 256, 0, stream>>>(
        out, Wb, bias, gamma, beta, out);
}

// Round 6
// 649.637 us; speedup vs baseline: 1.5677x; 1.5677x over previous
//
#include <hip/hip_runtime.h>

#define N_NODES 100000
#define N_EDGES 3200000
#define DIM 128
#define LN_EPS 1e-5f
#define NBLK 391              // ceil(N_NODES / 256)
#define N_BUCKETS 1563        // ceil(N_NODES / 64)
#define BUCKET_CAP 4096       // mean 2048, sigma ~45 -> no overflow
#define PART_BLOCKS 200
#define PART_CHUNK 16000      // 200 * 16000 = 3.2M

// ---- workspace layout (4-byte elements) ----
#define WS_CNT    0           // int  [N_NODES]
#define WS_OFF    100000      // int  [N_NODES+1]
#define WS_DIS    200004      // float[N_NODES]
#define WS_BIN    300004      // int  [N_EDGES]   packed (row | (col&63)<<17)
#define WS_BSUM   3500004     // int  [512]
#define WS_BEXC   3500516     // int  [512]
#define WS_BCUR   3501028     // int  [N_BUCKETS]
#define WS_WB     3502592     // 16384 bf16 (8192 ints)

typedef __attribute__((ext_vector_type(8))) short short8;   // bf16x8 MFMA frag
typedef __attribute__((ext_vector_type(4))) float floatx4;  // MFMA acc

__device__ __forceinline__ short f2bf(float f) {
    unsigned u = __float_as_uint(f);
    unsigned r = (u + 0x7FFFu + ((u >> 16) & 1u)) >> 16;   // RNE
    return (short)r;
}

// ---- degree count ----
__global__ void k_count(const int* __restrict__ col, int* __restrict__ cnt) {
    int e = blockIdx.x * blockDim.x + threadIdx.x;
    if (e < N_EDGES) atomicAdd(&cnt[col[e]], 1);
}

__global__ void k_blockreduce(const int* __restrict__ cnt, int* __restrict__ bsum) {
    __shared__ int s[256];
    int i = blockIdx.x * 256 + threadIdx.x;
    s[threadIdx.x] = (i < N_NODES) ? cnt[i] : 0;
    __syncthreads();
    for (int st = 128; st > 0; st >>= 1) {
        if (threadIdx.x < st) s[threadIdx.x] += s[threadIdx.x + st];
        __syncthreads();
    }
    if (threadIdx.x == 0) bsum[blockIdx.x] = s[0];
}

__global__ void k_scanbsums(const int* __restrict__ bsum, int* __restrict__ bexc,
                            int* __restrict__ off) {
    __shared__ int s[512];
    int t = threadIdx.x;
    int v0 = (t < NBLK) ? bsum[t] : 0;
    s[t] = v0;
    __syncthreads();
    for (int st = 1; st < 512; st <<= 1) {
        int v = (t >= st) ? s[t - st] : 0;
        __syncthreads();
        s[t] += v;
        __syncthreads();
    }
    if (t < NBLK) bexc[t] = s[t] - v0;
    if (t == 0) off[N_NODES] = N_EDGES;
}

__global__ void k_blockscan(const int* __restrict__ cnt, const int* __restrict__ bexc,
                            int* __restrict__ off) {
    __shared__ int s[256];
    int i = blockIdx.x * 256 + threadIdx.x;
    int v = (i < N_NODES) ? cnt[i] : 0;
    s[threadIdx.x] = v;
    __syncthreads();
    for (int st = 1; st < 256; st <<= 1) {
        int u = (threadIdx.x >= st) ? s[threadIdx.x - st] : 0;
        __syncthreads();
        s[threadIdx.x] += u;
        __syncthreads();
    }
    if (i < N_NODES) off[i] = bexc[blockIdx.x] + s[threadIdx.x] - v;  // exclusive
}

__global__ void k_dis(const int* __restrict__ cnt, float* __restrict__ dis) {
    int i = blockIdx.x * blockDim.x + threadIdx.x;
    if (i < N_NODES) dis[i] = rsqrtf(1.0f + (float)cnt[i]);
}

// ---- bucket cursors: bcur[b] = off[b*64] ----
__global__ void k_bcur(const int* __restrict__ off, int* __restrict__ bcur) {
    int b = blockIdx.x * blockDim.x + threadIdx.x;
    if (b < N_BUCKETS) bcur[b] = off[b << 6];
}

// ---- block-staged partition: per-block LDS histogram -> one global atomic per
// (block,bucket) -> contiguous runs per bucket (L2-merged writes, low contention)
__global__ void __launch_bounds__(256) k_binpack_staged(
        const int* __restrict__ row, const int* __restrict__ col,
        int* __restrict__ bcur, int* __restrict__ binned) {
    __shared__ int hist[N_BUCKETS];
    __shared__ int gpos[N_BUCKETS];
    int tid = threadIdx.x;
    int e0 = blockIdx.x * PART_CHUNK;
    int e1 = min(e0 + PART_CHUNK, N_EDGES);
    for (int t = tid; t < N_BUCKETS; t += 256) hist[t] = 0;
    __syncthreads();
    // pass A: local histogram
    for (int e = e0 + tid; e < e1; e += 256)
        atomicAdd(&hist[col[e] >> 6], 1);
    __syncthreads();
    // reserve global ranges; reset hist as local cursor
    for (int t = tid; t < N_BUCKETS; t += 256) {
        int h = hist[t];
        gpos[t] = h ? atomicAdd(&bcur[t], h) : 0;
        hist[t] = 0;
    }
    __syncthreads();
    // pass B: write packed edges into the block's contiguous runs
    for (int e = e0 + tid; e < e1; e += 256) {
        int c = col[e];
        int b = c >> 6;
        int lp = atomicAdd(&hist[b], 1);
        binned[gpos[b] + lp] = row[e] | ((c & 63) << 17);
    }
}

// ---- fused fine-sort (LDS) + gather: one block per bucket of 64 targets ----
__global__ void __launch_bounds__(256) k_bucket_gather(
        const float* __restrict__ x,
        const float* __restrict__ dis,
        const int* __restrict__ binned,
        const int* __restrict__ off,
        float* __restrict__ agg) {
    __shared__ int lcsr[BUCKET_CAP];
    __shared__ int lcur[64];
    int b = blockIdx.x;
    int node0 = b << 6;
    int nt = min(64, N_NODES - node0);    // 64, or 32 for the last bucket
    int tid = threadIdx.x;
    int base = off[node0];
    int cnt_b = off[node0 + nt] - base;
    if (tid < nt) lcur[tid] = off[node0 + tid] - base;
    __syncthreads();

    // fine scatter into LDS-local CSR (LDS atomics; no global scattered writes)
    for (int k = tid; k < cnt_b; k += 256) {
        int p = binned[base + k];
        int cl = p >> 17;
        int pos = atomicAdd(&lcur[cl], 1);
        lcsr[pos] = p & 0x1FFFF;
    }
    __syncthreads();

    // gather (R2-verified inner loop, sources from LDS)
    int wave = tid >> 6, lane = tid & 63;
    const float2* x2 = (const float2*)x;
    for (int u = 0; u < 16; ++u) {
        int node = node0 + wave * 16 + u;
        if (node >= N_NODES) break;
        int start = off[node] - base, end = off[node + 1] - base;
        float2 acc = make_float2(0.f, 0.f);
        for (int bs = start; bs < end; bs += 64) {
            int n = min(64, end - bs);
            int s = 0;
            float w = 0.f;
            if (lane < n) { s = lcsr[bs + lane]; w = dis[s]; }
            for (int j = 0; j < n; ++j) {
                int sj = __shfl(s, j, 64);
                float wj = __shfl(w, j, 64);
                float2 xv = x2[(size_t)sj * 64 + lane];   // 512B coalesced row read
                acc.x += wj * xv.x;
                acc.y += wj * xv.y;
            }
        }
        float di = dis[node];
        float2 xi = x2[(size_t)node * 64 + lane];
        acc.x = (acc.x + di * xi.x) * di;
        acc.y = (acc.y + di * xi.y) * di;
        ((float2*)agg)[(size_t)node * 64 + lane] = acc;
    }
}

// ---- W fp32 -> bf16 ----
__global__ void k_wconv(const float* __restrict__ W, short* __restrict__ Wb) {
    int i = blockIdx.x * 256 + threadIdx.x;
    if (i < DIM * DIM) Wb[i] = f2bf(W[i]);
}

// ---- linear + LayerNorm via bf16 MFMA: one wave per 16 nodes, in-place on agg/out ----
// mfma_f32_16x16x32_bf16: A[m=lane&15][k=(lane>>4)*8+j]; C/D: col=lane&15, row=(lane>>4)*4+reg
// NOTE: agg/out intentionally NOT __restrict__ (same buffer, in-place).
__global__ void __launch_bounds__(256) k_linear_ln_mfma(
        const float* agg,
        const short* __restrict__ Wb,
        const float* __restrict__ bias,
        const float* __restrict__ gamma,
        const float* __restrict__ beta,
        float* out) {
    int wave = threadIdx.x >> 6;
    int lane = threadIdx.x & 63;
    int i0 = (blockIdx.x * 4 + wave) * 16;   // 16 nodes per wave; 100000 % 16 == 0
    if (i0 >= N_NODES) return;
    int m = lane & 15;
    int q = lane >> 4;

    floatx4 acc[8];
#pragma unroll
    for (int t = 0; t < 8; ++t) acc[t] = (floatx4){0.f, 0.f, 0.f, 0.f};

#pragma unroll
    for (int s = 0; s < 4; ++s) {
        int k0 = s * 32 + q * 8;
        const float* ap = agg + (size_t)(i0 + m) * DIM + k0;
        float4 a0 = *(const float4*)ap;
        float4 a1 = *(const float4*)(ap + 4);
        short8 af;
        af[0] = f2bf(a0.x); af[1] = f2bf(a0.y); af[2] = f2bf(a0.z); af[3] = f2bf(a0.w);
        af[4] = f2bf(a1.x); af[5] = f2bf(a1.y); af[6] = f2bf(a1.z); af[7] = f2bf(a1.w);
#pragma unroll
        for (int t = 0; t < 8; ++t) {
            short8 bf = *(const short8*)(Wb + (size_t)(t * 16 + m) * DIM + k0);
            acc[t] = __builtin_amdgcn_mfma_f32_16x16x32_bf16(af, bf, acc[t], 0, 0, 0);
        }
    }

    float bv[8], gv[8], btv[8];
#pragma unroll
    for (int t = 0; t < 8; ++t) {
        int dim = t * 16 + m;
        bv[t] = bias[dim]; gv[t] = gamma[dim]; btv[t] = beta[dim];
    }
    float S[4], S2[4];
#pragma unroll
    for (int r = 0; r < 4; ++r) {
        float s = 0.f, s2 = 0.f;
#pragma unroll
        for (int t = 0; t < 8; ++t) {
            float v = acc[t][r] + bv[t];
            s += v; s2 += v * v;
        }
        S[r] = s; S2[r] = s2;
    }
#pragma unroll
    for (int mask = 1; mask < 16; mask <<= 1) {
#pragma unroll
        for (int r = 0; r < 4; ++r) {
            S[r]  += __shfl_xor(S[r],  mask, 64);
            S2[r] += __shfl_xor(S2[r], mask, 64);
        }
    }
#pragma unroll
    for (int r = 0; r < 4; ++r) {
        float mean = S[r] * (1.0f / DIM);
        float var  = S2[r] * (1.0f / DIM) - mean * mean;
        float inv  = rsqrtf(var + LN_EPS);
        int node = i0 + q * 4 + r;
#pragma unroll
        for (int t = 0; t < 8; ++t) {
            float v = acc[t][r] + bv[t];
            out[(size_t)node * DIM + t * 16 + m] = (v - mean) * inv * gv[t] + btv[t];
        }
    }
}

extern "C" void kernel_launch(void* const* d_in, const int* in_sizes, int n_in,
                              void* d_out, int out_size, void* d_ws, size_t ws_size,
                              hipStream_t stream) {
    const float* x     = (const float*)d_in[0];
    const int*   row   = (const int*)d_in[1];                // edge_index[0] (sources)
    const int*   col   = ((const int*)d_in[1]) + N_EDGES;    // edge_index[1] (targets)
    const float* W     = (const float*)d_in[2];
    const float* bias  = (const float*)d_in[3];
    const float* gamma = (const float*)d_in[4];
    const float* beta  = (const float*)d_in[5];
    float* out = (float*)d_out;

    int*   wsi    = (int*)d_ws;
    int*   cnt    = wsi + WS_CNT;
    int*   off    = wsi + WS_OFF;
    float* dis    = (float*)(wsi + WS_DIS);
    int*   binned = wsi + WS_BIN;
    int*   bsum   = wsi + WS_BSUM;
    int*   bexc   = wsi + WS_BEXC;
    int*   bcur   = wsi + WS_BCUR;
    short* Wb     = (short*)(wsi + WS_WB);

    hipMemsetAsync(cnt, 0, N_NODES * sizeof(int), stream);

    k_wconv<<<(DIM * DIM + 255) / 256, 256, 0, stream>>>(W, Wb);
    k_count<<<(N_EDGES + 255) / 256, 256, 0, stream>>>(col, cnt);
    k_blockreduce<<<NBLK, 256, 0, stream>>>(cnt, bsum);
    k_scanbsums<<<1, 512, 0, stream>>>(bsum, bexc, off);
    k_blockscan<<<NBLK, 256, 0, stream>>>(cnt, bexc, off);
    k_dis<<<NBLK, 256, 0, stream>>>(cnt, dis);
    k_bcur<<<(N_BUCKETS + 255) / 256, 256, 0, stream>>>(off, bcur);
    k_binpack_staged<<<PART_BLOCKS, 256, 0, stream>>>(row, col, bcur, binned);

    k_bucket_gather<<<N_BUCKETS, 256, 0, stream>>>(x, dis, binned, off, out);

    k_linear_ln_mfma<<<(N_NODES / 16 + 3) / 4, 256, 0, stream>>>(
        out, Wb, bias, gamma, beta, out);
}

// Round 7
// 624.219 us; speedup vs baseline: 1.6315x; 1.0407x over previous
//
#include <hip/hip_runtime.h>

#define N_NODES 100000
#define N_EDGES 3200000
#define DIM 128
#define LN_EPS 1e-5f
#define NBLK 391              // ceil(N_NODES / 256)
#define N_BUCKETS 1563        // ceil(N_NODES / 64)
#define BUCKET_CAP 4096       // mean 2048, sigma ~45 -> no overflow
#define PART_BLOCKS 200
#define PART_CHUNK 16000      // 200 * 16000 = 3.2M

// ---- workspace layout (4-byte elements) ----
#define WS_CNT    0           // int  [N_NODES]
#define WS_OFF    100000      // int  [N_NODES+1]
#define WS_DIS    200004      // float[N_NODES]
#define WS_BIN    300004      // int  [N_EDGES]   packed (row | (col&63)<<17)
#define WS_BSUM   3500004     // int  [512]
#define WS_BEXC   3500516     // int  [512]
#define WS_BCUR   3501028     // int  [N_BUCKETS]
#define WS_WB     3502592     // 16384 bf16 (8192 ints)
#define WS_XW     3510784     // 12.8M bf16 (6.4M ints) -- fused path only
#define WS_FUSED_BYTES ((size_t)(WS_XW + 6400000) * 4)

typedef __attribute__((ext_vector_type(8))) short short8;   // bf16x8 MFMA frag
typedef __attribute__((ext_vector_type(4))) float floatx4;  // MFMA acc

__device__ __forceinline__ short f2bf(float f) {
    unsigned u = __float_as_uint(f);
    unsigned r = (u + 0x7FFFu + ((u >> 16) & 1u)) >> 16;   // RNE
    return (short)r;
}
__device__ __forceinline__ float bf2f(unsigned short h) {
    return __uint_as_float(((unsigned)h) << 16);
}

// ---- degree count ----
__global__ void k_count(const int* __restrict__ col, int* __restrict__ cnt) {
    int e = blockIdx.x * blockDim.x + threadIdx.x;
    if (e < N_EDGES) atomicAdd(&cnt[col[e]], 1);
}

__global__ void k_blockreduce(const int* __restrict__ cnt, int* __restrict__ bsum) {
    __shared__ int s[256];
    int i = blockIdx.x * 256 + threadIdx.x;
    s[threadIdx.x] = (i < N_NODES) ? cnt[i] : 0;
    __syncthreads();
    for (int st = 128; st > 0; st >>= 1) {
        if (threadIdx.x < st) s[threadIdx.x] += s[threadIdx.x + st];
        __syncthreads();
    }
    if (threadIdx.x == 0) bsum[blockIdx.x] = s[0];
}

__global__ void k_scanbsums(const int* __restrict__ bsum, int* __restrict__ bexc,
                            int* __restrict__ off) {
    __shared__ int s[512];
    int t = threadIdx.x;
    int v0 = (t < NBLK) ? bsum[t] : 0;
    s[t] = v0;
    __syncthreads();
    for (int st = 1; st < 512; st <<= 1) {
        int v = (t >= st) ? s[t - st] : 0;
        __syncthreads();
        s[t] += v;
        __syncthreads();
    }
    if (t < NBLK) bexc[t] = s[t] - v0;
    if (t == 0) off[N_NODES] = N_EDGES;
}

__global__ void k_blockscan(const int* __restrict__ cnt, const int* __restrict__ bexc,
                            int* __restrict__ off) {
    __shared__ int s[256];
    int i = blockIdx.x * 256 + threadIdx.x;
    int v = (i < N_NODES) ? cnt[i] : 0;
    s[threadIdx.x] = v;
    __syncthreads();
    for (int st = 1; st < 256; st <<= 1) {
        int u = (threadIdx.x >= st) ? s[threadIdx.x - st] : 0;
        __syncthreads();
        s[threadIdx.x] += u;
        __syncthreads();
    }
    if (i < N_NODES) off[i] = bexc[blockIdx.x] + s[threadIdx.x] - v;  // exclusive
}

__global__ void k_dis(const int* __restrict__ cnt, float* __restrict__ dis) {
    int i = blockIdx.x * blockDim.x + threadIdx.x;
    if (i < N_NODES) dis[i] = rsqrtf(1.0f + (float)cnt[i]);
}

// ---- bucket cursors: bcur[b] = off[b*64] ----
__global__ void k_bcur(const int* __restrict__ off, int* __restrict__ bcur) {
    int b = blockIdx.x * blockDim.x + threadIdx.x;
    if (b < N_BUCKETS) bcur[b] = off[b << 6];
}

// ---- block-staged partition (R6-verified) ----
__global__ void __launch_bounds__(256) k_binpack_staged(
        const int* __restrict__ row, const int* __restrict__ col,
        int* __restrict__ bcur, int* __restrict__ binned) {
    __shared__ int hist[N_BUCKETS];
    __shared__ int gpos[N_BUCKETS];
    int tid = threadIdx.x;
    int e0 = blockIdx.x * PART_CHUNK;
    int e1 = min(e0 + PART_CHUNK, N_EDGES);
    for (int t = tid; t < N_BUCKETS; t += 256) hist[t] = 0;
    __syncthreads();
    for (int e = e0 + tid; e < e1; e += 256)
        atomicAdd(&hist[col[e] >> 6], 1);
    __syncthreads();
    for (int t = tid; t < N_BUCKETS; t += 256) {
        int h = hist[t];
        gpos[t] = h ? atomicAdd(&bcur[t], h) : 0;
        hist[t] = 0;
    }
    __syncthreads();
    for (int e = e0 + tid; e < e1; e += 256) {
        int c = col[e];
        int b = c >> 6;
        int lp = atomicAdd(&hist[b], 1);
        binned[gpos[b] + lp] = row[e] | ((c & 63) << 17);
    }
}

// ---- W fp32 -> bf16 ----
__global__ void k_wconv(const float* __restrict__ W, short* __restrict__ Wb) {
    int i = blockIdx.x * 256 + threadIdx.x;
    if (i < DIM * DIM) Wb[i] = f2bf(W[i]);
}

// ---- xW = x @ W^T in bf16 (same verified MFMA structure as the linear, no LN) ----
__global__ void __launch_bounds__(256) k_xw(
        const float* __restrict__ x,
        const short* __restrict__ Wb,
        unsigned short* __restrict__ xw) {
    int wave = threadIdx.x >> 6;
    int lane = threadIdx.x & 63;
    int i0 = (blockIdx.x * 4 + wave) * 16;
    if (i0 >= N_NODES) return;
    int m = lane & 15;
    int q = lane >> 4;

    floatx4 acc[8];
#pragma unroll
    for (int t = 0; t < 8; ++t) acc[t] = (floatx4){0.f, 0.f, 0.f, 0.f};

#pragma unroll
    for (int s = 0; s < 4; ++s) {
        int k0 = s * 32 + q * 8;
        const float* ap = x + (size_t)(i0 + m) * DIM + k0;
        float4 a0 = *(const float4*)ap;
        float4 a1 = *(const float4*)(ap + 4);
        short8 af;
        af[0] = f2bf(a0.x); af[1] = f2bf(a0.y); af[2] = f2bf(a0.z); af[3] = f2bf(a0.w);
        af[4] = f2bf(a1.x); af[5] = f2bf(a1.y); af[6] = f2bf(a1.z); af[7] = f2bf(a1.w);
#pragma unroll
        for (int t = 0; t < 8; ++t) {
            short8 bf = *(const short8*)(Wb + (size_t)(t * 16 + m) * DIM + k0);
            acc[t] = __builtin_amdgcn_mfma_f32_16x16x32_bf16(af, bf, acc[t], 0, 0, 0);
        }
    }
    // C/D: col=lane&15, row=(lane>>4)*4+reg
#pragma unroll
    for (int r = 0; r < 4; ++r) {
        int node = i0 + q * 4 + r;
#pragma unroll
        for (int t = 0; t < 8; ++t)
            xw[(size_t)node * DIM + t * 16 + m] = (unsigned short)f2bf(acc[t][r]);
    }
}

// ---- fused fine-sort + gather over bf16 xW + bias + LayerNorm ----
__global__ void __launch_bounds__(256) k_gather_fused(
        const unsigned short* __restrict__ xw,
        const float* __restrict__ dis,
        const int* __restrict__ binned,
        const int* __restrict__ off,
        const float* __restrict__ bias,
        const float* __restrict__ gamma,
        const float* __restrict__ beta,
        float* __restrict__ out) {
    __shared__ int lcsr[BUCKET_CAP];
    __shared__ int lcur[64];
    int b = blockIdx.x;
    int node0 = b << 6;
    int nt = min(64, N_NODES - node0);
    int tid = threadIdx.x;
    int base = off[node0];
    int cnt_b = off[node0 + nt] - base;
    if (tid < nt) lcur[tid] = off[node0 + tid] - base;
    __syncthreads();

    for (int k = tid; k < cnt_b; k += 256) {
        int p = binned[base + k];
        int cl = p >> 17;
        int pos = atomicAdd(&lcur[cl], 1);
        lcsr[pos] = p & 0x1FFFF;
    }
    __syncthreads();

    int wave = tid >> 6, lane = tid & 63;
    const ushort2* xw2 = (const ushort2*)xw;   // 2 dims per lane
    float2 bi = ((const float2*)bias)[lane];
    float2 ga = ((const float2*)gamma)[lane];
    float2 be = ((const float2*)beta)[lane];

    for (int u = 0; u < 16; ++u) {
        int node = node0 + wave * 16 + u;
        if (node >= N_NODES) break;
        int start = off[node] - base, end = off[node + 1] - base;
        float2 acc = make_float2(0.f, 0.f);
        for (int bs = start; bs < end; bs += 64) {
            int n = min(64, end - bs);
            int s = 0;
            float w = 0.f;
            if (lane < n) { s = lcsr[bs + lane]; w = dis[s]; }
            for (int j = 0; j < n; ++j) {
                int sj = __shfl(s, j, 64);
                float wj = __shfl(w, j, 64);
                ushort2 uv = xw2[(size_t)sj * 64 + lane];   // 256B coalesced row read
                acc.x += wj * bf2f(uv.x);
                acc.y += wj * bf2f(uv.y);
            }
        }
        float di = dis[node];
        ushort2 ui = xw2[(size_t)node * 64 + lane];
        float v0 = (acc.x + di * bf2f(ui.x)) * di + bi.x;
        float v1 = (acc.y + di * bf2f(ui.y)) * di + bi.y;

        // LayerNorm across the wave's 128 dims
        float S = v0 + v1, S2 = v0 * v0 + v1 * v1;
#pragma unroll
        for (int mask = 1; mask < 64; mask <<= 1) {
            S  += __shfl_xor(S,  mask, 64);
            S2 += __shfl_xor(S2, mask, 64);
        }
        float mean = S * (1.0f / DIM);
        float var  = S2 * (1.0f / DIM) - mean * mean;
        float inv  = rsqrtf(var + LN_EPS);
        float2 o;
        o.x = (v0 - mean) * inv * ga.x + be.x;
        o.y = (v1 - mean) * inv * ga.y + be.y;
        ((float2*)out)[(size_t)node * 64 + lane] = o;
    }
}

// ================= fallback path (R6-verified) =================
__global__ void __launch_bounds__(256) k_bucket_gather(
        const float* __restrict__ x,
        const float* __restrict__ dis,
        const int* __restrict__ binned,
        const int* __restrict__ off,
        float* __restrict__ agg) {
    __shared__ int lcsr[BUCKET_CAP];
    __shared__ int lcur[64];
    int b = blockIdx.x;
    int node0 = b << 6;
    int nt = min(64, N_NODES - node0);
    int tid = threadIdx.x;
    int base = off[node0];
    int cnt_b = off[node0 + nt] - base;
    if (tid < nt) lcur[tid] = off[node0 + tid] - base;
    __syncthreads();
    for (int k = tid; k < cnt_b; k += 256) {
        int p = binned[base + k];
        int cl = p >> 17;
        int pos = atomicAdd(&lcur[cl], 1);
        lcsr[pos] = p & 0x1FFFF;
    }
    __syncthreads();
    int wave = tid >> 6, lane = tid & 63;
    const float2* x2 = (const float2*)x;
    for (int u = 0; u < 16; ++u) {
        int node = node0 + wave * 16 + u;
        if (node >= N_NODES) break;
        int start = off[node] - base, end = off[node + 1] - base;
        float2 acc = make_float2(0.f, 0.f);
        for (int bs = start; bs < end; bs += 64) {
            int n = min(64, end - bs);
            int s = 0;
            float w = 0.f;
            if (lane < n) { s = lcsr[bs + lane]; w = dis[s]; }
            for (int j = 0; j < n; ++j) {
                int sj = __shfl(s, j, 64);
                float wj = __shfl(w, j, 64);
                float2 xv = x2[(size_t)sj * 64 + lane];
                acc.x += wj * xv.x;
                acc.y += wj * xv.y;
            }
        }
        float di = dis[node];
        float2 xi = x2[(size_t)node * 64 + lane];
        acc.x = (acc.x + di * xi.x) * di;
        acc.y = (acc.y + di * xi.y) * di;
        ((float2*)agg)[(size_t)node * 64 + lane] = acc;
    }
}

__global__ void __launch_bounds__(256) k_linear_ln_mfma(
        const float* agg,
        const short* __restrict__ Wb,
        const float* __restrict__ bias,
        const float* __restrict__ gamma,
        const float* __restrict__ beta,
        float* out) {
    int wave = threadIdx.x >> 6;
    int lane = threadIdx.x & 63;
    int i0 = (blockIdx.x * 4 + wave) * 16;
    if (i0 >= N_NODES) return;
    int m = lane & 15;
    int q = lane >> 4;
    floatx4 acc[8];
#pragma unroll
    for (int t = 0; t < 8; ++t) acc[t] = (floatx4){0.f, 0.f, 0.f, 0.f};
#pragma unroll
    for (int s = 0; s < 4; ++s) {
        int k0 = s * 32 + q * 8;
        const float* ap = agg + (size_t)(i0 + m) * DIM + k0;
        float4 a0 = *(const float4*)ap;
        float4 a1 = *(const float4*)(ap + 4);
        short8 af;
        af[0] = f2bf(a0.x); af[1] = f2bf(a0.y); af[2] = f2bf(a0.z); af[3] = f2bf(a0.w);
        af[4] = f2bf(a1.x); af[5] = f2bf(a1.y); af[6] = f2bf(a1.z); af[7] = f2bf(a1.w);
#pragma unroll
        for (int t = 0; t < 8; ++t) {
            short8 bf = *(const short8*)(Wb + (size_t)(t * 16 + m) * DIM + k0);
            acc[t] = __builtin_amdgcn_mfma_f32_16x16x32_bf16(af, bf, acc[t], 0, 0, 0);
        }
    }
    float bv[8], gv[8], btv[8];
#pragma unroll
    for (int t = 0; t < 8; ++t) {
        int dim = t * 16 + m;
        bv[t] = bias[dim]; gv[t] = gamma[dim]; btv[t] = beta[dim];
    }
    float S[4], S2[4];
#pragma unroll
    for (int r = 0; r < 4; ++r) {
        float s = 0.f, s2 = 0.f;
#pragma unroll
        for (int t = 0; t < 8; ++t) {
            float v = acc[t][r] + bv[t];
            s += v; s2 += v * v;
        }
        S[r] = s; S2[r] = s2;
    }
#pragma unroll
    for (int mask = 1; mask < 16; mask <<= 1) {
#pragma unroll
        for (int r = 0; r < 4; ++r) {
            S[r]  += __shfl_xor(S[r],  mask, 64);
            S2[r] += __shfl_xor(S2[r], mask, 64);
        }
    }
#pragma unroll
    for (int r = 0; r < 4; ++r) {
        float mean = S[r] * (1.0f / DIM);
        float var  = S2[r] * (1.0f / DIM) - mean * mean;
        float inv  = rsqrtf(var + LN_EPS);
        int node = i0 + q * 4 + r;
#pragma unroll
        for (int t = 0; t < 8; ++t) {
            float v = acc[t][r] + bv[t];
            out[(size_t)node * DIM + t * 16 + m] = (v - mean) * inv * gv[t] + btv[t];
        }
    }
}

extern "C" void kernel_launch(void* const* d_in, const int* in_sizes, int n_in,
                              void* d_out, int out_size, void* d_ws, size_t ws_size,
                              hipStream_t stream) {
    const float* x     = (const float*)d_in[0];
    const int*   row   = (const int*)d_in[1];
    const int*   col   = ((const int*)d_in[1]) + N_EDGES;
    const float* W     = (const float*)d_in[2];
    const float* bias  = (const float*)d_in[3];
    const float* gamma = (const float*)d_in[4];
    const float* beta  = (const float*)d_in[5];
    float* out = (float*)d_out;

    int*   wsi    = (int*)d_ws;
    int*   cnt    = wsi + WS_CNT;
    int*   off    = wsi + WS_OFF;
    float* dis    = (float*)(wsi + WS_DIS);
    int*   binned = wsi + WS_BIN;
    int*   bsum   = wsi + WS_BSUM;
    int*   bexc   = wsi + WS_BEXC;
    int*   bcur   = wsi + WS_BCUR;
    short* Wb     = (short*)(wsi + WS_WB);
    unsigned short* xw = (unsigned short*)(wsi + WS_XW);

    bool fused = ws_size >= WS_FUSED_BYTES;

    hipMemsetAsync(cnt, 0, N_NODES * sizeof(int), stream);

    k_wconv<<<(DIM * DIM + 255) / 256, 256, 0, stream>>>(W, Wb);
    if (fused)
        k_xw<<<(N_NODES / 16 + 3) / 4, 256, 0, stream>>>(x, Wb, xw);
    k_count<<<(N_EDGES + 255) / 256, 256, 0, stream>>>(col, cnt);
    k_blockreduce<<<NBLK, 256, 0, stream>>>(cnt, bsum);
    k_scanbsums<<<1, 512, 0, stream>>>(bsum, bexc, off);
    k_blockscan<<<NBLK, 256, 0, stream>>>(cnt, bexc, off);
    k_dis<<<NBLK, 256, 0, stream>>>(cnt, dis);
    k_bcur<<<(N_BUCKETS + 255) / 256, 256, 0, stream>>>(off, bcur);
    k_binpack_staged<<<PART_BLOCKS, 256, 0, stream>>>(row, col, bcur, binned);

    if (fused) {
        k_gather_fused<<<N_BUCKETS, 256, 0, stream>>>(
            xw, dis, binned, off, bias, gamma, beta, out);
    } else {
        k_bucket_gather<<<N_BUCKETS, 256, 0, stream>>>(x, dis, binned, off, out);
        k_linear_ln_mfma<<<(N_NODES / 16 + 3) / 4, 256, 0, stream>>>(
            out, Wb, bias, gamma, beta, out);
    }
}